// Round 3
// baseline (495.719 us; speedup 1.0000x reference)
//
#include <hip/hip_runtime.h>
#include <hip/hip_fp16.h>
#include <math.h>

#define NIMG 8
#define PNUM 4000
#define CNUM 91
#define DETK 100
#define NEGV  -1000000000.0
#define NEGH  -500000000.0
#define CLAMP64 4.1351665567423558   // float64 nearest to log(1000/16)

// Fully fused FastRCNN postprocess: one block per image, all state in LDS.
// All decision-feeding math in float64 to match the numpy (f64) reference's
// discrete choices (argmax order, validity, IoU>0.5) exactly.
// Output d_out is FLOAT32: [800 labels | 800 scores | 3200 boxes] flat.
extern "C" __global__ __launch_bounds__(1024)
void k_fused(const float* __restrict__ logits,   // [8][4000][91]
             const float* __restrict__ deltas,   // [8][4000][364]
             const float* __restrict__ props,    // [8][4000][4]
             float* __restrict__ out)            // [4800] f32
{
    __shared__ float   bh0[PNUM], bh1[PNUM], bh2[PNUM], bh3[PNUM]; // box hi (f32)
    __shared__ __half  bl0[PNUM], bl1[PNUM], bl2[PNUM], bl3[PNUM]; // box lo (f16)
    __shared__ double  act[PNUM];
    __shared__ unsigned short slab[PNUM];
    __shared__ double  redV[16];
    __shared__ int     redI[16];
    __shared__ double  pbox[4];
    __shared__ int     pidx, pkeep, plab;
    __shared__ int     kidx[DETK], kkeep[DETK];
    __shared__ double  kscore[DETK];
    __shared__ double  kbox[DETK][4];

    const int n   = blockIdx.x;
    const int tid = threadIdx.x;

    // ---------------- Phase A: softmax + label + f64 decode ----------------
    for (int j = tid; j < PNUM; j += 1024) {
        const long q = (long)n * PNUM + j;
        const float* lg = logits + q * CNUM;

        // max over all 91 (exact: comparisons only), fg argmax (first-occurrence)
        float ml = lg[0];
        float bv = lg[1];
        int   lab = 1;
        for (int c = 1; c < CNUM; ++c) {
            const float v = lg[c];
            ml = fmaxf(ml, v);
            if (c >= 2 && v > bv) { bv = v; lab = c; }  // strict > keeps first max
        }

        const double m = (double)ml;
        double sum = 0.0;
        for (int c = 0; c < CNUM; ++c) sum += exp((double)lg[c] - m);
        const double score = exp((double)bv - m) / sum;

        // f64 decode of the label-selected deltas
        const float* pr = props + q * 4;
        const double x1p = (double)pr[0], y1p = (double)pr[1];
        const double x2p = (double)pr[2], y2p = (double)pr[3];
        const double w  = x2p - x1p, h = y2p - y1p;
        const double cx = x1p + 0.5 * w, cy = y1p + 0.5 * h;

        const float* dl = deltas + q * (CNUM * 4) + lab * 4;
        const double dx = (double)dl[0] / 10.0;
        const double dy = (double)dl[1] / 10.0;
        const double dw = fmin((double)dl[2] / 5.0, CLAMP64);
        const double dh = fmin((double)dl[3] / 5.0, CLAMP64);

        const double pcx = dx * w + cx;
        const double pcy = dy * h + cy;
        const double pw  = exp(dw) * w;
        const double ph  = exp(dh) * h;

        double x1 = pcx - 0.5 * pw, y1 = pcy - 0.5 * ph;
        double x2 = pcx + 0.5 * pw, y2 = pcy + 0.5 * ph;
        x1 = fmin(fmax(x1, 0.0), 800.0);
        y1 = fmin(fmax(y1, 0.0), 800.0);
        x2 = fmin(fmax(x2, 0.0), 800.0);
        y2 = fmin(fmax(y2, 0.0), 800.0);

        const bool valid = ((x2 - x1) >= 0.01) && ((y2 - y1) >= 0.01) && (score > 0.05);

        act[j]  = valid ? score : NEGV;
        slab[j] = (unsigned short)lab;

        // hi/lo split: coord ~= (double)hi + (double)lo, error <= ~6e-8
        const float h0 = (float)x1, h1 = (float)y1, h2 = (float)x2, h3 = (float)y2;
        bh0[j] = h0; bh1[j] = h1; bh2[j] = h2; bh3[j] = h3;
        bl0[j] = __float2half((float)(x1 - (double)h0));
        bl1[j] = __float2half((float)(y1 - (double)h1));
        bl2[j] = __float2half((float)(x2 - (double)h2));
        bl3[j] = __float2half((float)(y2 - (double)h3));
    }
    __syncthreads();

    // ---------------- Phase B: 100 x (argmax + suppress) ----------------
    for (int k = 0; k < DETK; ++k) {
        // block argmax over f64 act with lowest-index tie-break
        double bv = -INFINITY;
        int    bi = 0x7fffffff;
        #pragma unroll
        for (int t = 0; t < 4; ++t) {
            const int j = tid + t * 1024;
            if (j < PNUM) {
                const double v = act[j];
                if (v > bv) { bv = v; bi = j; }   // ascending j => first max kept
            }
        }
        #pragma unroll
        for (int s = 32; s; s >>= 1) {
            const double ov = __shfl_xor(bv, s);
            const int    oi = __shfl_xor(bi, s);
            if (ov > bv || (ov == bv && oi < bi)) { bv = ov; bi = oi; }
        }
        if ((tid & 63) == 0) { redV[tid >> 6] = bv; redI[tid >> 6] = bi; }
        __syncthreads();
        if (tid < 64) {
            bv = (tid < 16) ? redV[tid] : -INFINITY;
            bi = (tid < 16) ? redI[tid] : 0x7fffffff;
            #pragma unroll
            for (int s = 8; s; s >>= 1) {
                const double ov = __shfl_xor(bv, s);
                const int    oi = __shfl_xor(bi, s);
                if (ov > bv || (ov == bv && oi < bi)) { bv = ov; bi = oi; }
            }
            if (tid == 0) {
                const int kp = (bv > NEGH) ? 1 : 0;
                pidx = bi; pkeep = kp; plab = (int)slab[bi];
                kidx[k] = bi; kkeep[k] = kp; kscore[k] = bv;
                const double b0 = (double)bh0[bi] + (double)__half2float(bl0[bi]);
                const double b1 = (double)bh1[bi] + (double)__half2float(bl1[bi]);
                const double b2 = (double)bh2[bi] + (double)__half2float(bl2[bi]);
                const double b3 = (double)bh3[bi] + (double)__half2float(bl3[bi]);
                pbox[0] = b0; pbox[1] = b1; pbox[2] = b2; pbox[3] = b3;
                kbox[k][0] = b0; kbox[k][1] = b1; kbox[k][2] = b2; kbox[k][3] = b3;
            }
        }
        __syncthreads();

        // suppression (same-label only; cross-label suppression is provably a no-op)
        const int    pick = pidx;
        const int    kp   = pkeep;
        const int    pl   = plab;
        const double px1 = pbox[0], py1 = pbox[1], px2 = pbox[2], py2 = pbox[3];
        const double a1  = (px2 - px1) * (py2 - py1);
        #pragma unroll
        for (int t = 0; t < 4; ++t) {
            const int j = tid + t * 1024;
            if (j >= PNUM) break;
            if (j == pick) { act[j] = NEGV; continue; }
            if (!kp) continue;
            if ((int)slab[j] != pl) continue;
            if (act[j] <= NEGH) continue;           // already NEG: suppression is a no-op
            const double qx1 = (double)bh0[j] + (double)__half2float(bl0[j]);
            const double qy1 = (double)bh1[j] + (double)__half2float(bl1[j]);
            const double qx2 = (double)bh2[j] + (double)__half2float(bl2[j]);
            const double qy2 = (double)bh3[j] + (double)__half2float(bl3[j]);
            const double ix = fmin(px2, qx2) - fmax(px1, qx1);
            const double iy = fmin(py2, qy2) - fmax(py1, qy1);
            const double inter = fmax(ix, 0.0) * fmax(iy, 0.0);
            const double a2  = (qx2 - qx1) * (qy2 - qy1);
            const double uni = fmax(a1 + a2 - inter, 1e-9);
            if (inter / uni > 0.5) act[j] = NEGV;
        }
        __syncthreads();
    }

    // ---------------- gather: [labels | scores | boxes] as FLOAT32 ----------------
    if (tid < DETK) {
        const int kp = kkeep[tid];
        const int o  = n * DETK + tid;
        out[o]               = kp ? (float)slab[kidx[tid]] : 0.0f;
        out[NIMG * DETK + o] = kp ? (float)kscore[tid] : 0.0f;
        #pragma unroll
        for (int i = 0; i < 4; ++i) {
            out[2 * NIMG * DETK + o * 4 + i] = kp ? (float)kbox[tid][i] : 0.0f;
        }
    }
}

extern "C" void kernel_launch(void* const* d_in, const int* in_sizes, int n_in,
                              void* d_out, int out_size, void* d_ws, size_t ws_size,
                              hipStream_t stream)
{
    // inputs: [0]=images (unused; H=W=800), [1]=class_logits, [2]=pred_bbox_deltas, [3]=proposals
    const float* logits = (const float*)d_in[1];
    const float* deltas = (const float*)d_in[2];
    const float* props  = (const float*)d_in[3];
    float* out = (float*)d_out;

    hipLaunchKernelGGL(k_fused, dim3(NIMG), dim3(1024), 0, stream,
                       logits, deltas, props, out);
}